// Round 11
// baseline (3258.627 us; speedup 1.0000x reference)
//
#include <hip/hip_runtime.h>
#include <stdint.h>

#define T_STEPS 200
#define OBSD    128
#define HID     128
#define LATD    32
#define BS_TOT  12800
#define KIN     160

#define OUT_ENT_OFF 81920000
#define OUT_LP_OFF  84480000
#define WS_XG_BYTES 52428800   // xg region size in ws; Wr frags live after it

// lstm_main LDS layout (bytes) — 28 KB/block -> 2 blocks/CU
#define H_OFF   0          // 2 x 8192 : h [32][128] bf16, XOR-swizzled, dbuf
#define WMU_OFF 16384      // 8192     : W_mu bf16 [32][128], XOR-swizzled
#define E_OFF   24576      // 2 x 2048 : eps bf16 A-frag order, dbuf
#define LDS_SZ  28672

#define L2E  1.4426950408889634f
#define L2E2 2.8853900817779268f
#define LOG2PI 1.8378770664093453f

typedef short  bf16x8 __attribute__((ext_vector_type(8)));
typedef float  f32x4  __attribute__((ext_vector_type(4)));
typedef uint32_t u32;

// raw workgroup barrier: order LDS only, leave global loads/stores in flight
#define BAR() do {                                        \
    __builtin_amdgcn_sched_barrier(0);                    \
    asm volatile("s_waitcnt lgkmcnt(0)" ::: "memory");    \
    __builtin_amdgcn_s_barrier();                         \
    __builtin_amdgcn_sched_barrier(0);                    \
} while (0)

__device__ __forceinline__ uint16_t f2bf(float f) {
    u32 u = __builtin_bit_cast(u32, f);
    u32 r = (u + 0x7fffu + ((u >> 16) & 1u)) >> 16;
    return (uint16_t)r;
}
__device__ __forceinline__ u32 pack2(float a, float b) {
    return (u32)f2bf(a) | ((u32)f2bf(b) << 16);
}
__device__ __forceinline__ u32 cvt_pk_bf16(float lo, float hi) {
    u32 r;
    asm("v_cvt_pk_bf16_f32 %0, %1, %2" : "=v"(r) : "v"(lo), "v"(hi));
    return r;
}
__device__ __forceinline__ float sig2(float x) {   // x pre-scaled by L2E
    float e;
    asm("v_exp_f32 %0, -%1" : "=v"(e) : "v"(x));
    return __builtin_amdgcn_rcpf(1.f + e);
}
__device__ __forceinline__ float tanh2(float x) {  // x pre-scaled by 2*L2E
    float e;
    asm("v_exp_f32 %0, %1" : "=v"(e) : "v"(x));
    return 1.f - 2.f * __builtin_amdgcn_rcpf(1.f + e);
}
__device__ __forceinline__ int hswz(int row, int col) {
    return ((row << 8) + (col << 1)) ^ ((row & 7) << 4);
}
__device__ __forceinline__ f32x4 cfrag(u32 u01, u32 u23) {
    f32x4 c;
    c[0] = __builtin_bit_cast(float, u01 << 16);
    c[1] = __builtin_bit_cast(float, u01 & 0xffff0000u);
    c[2] = __builtin_bit_cast(float, u23 << 16);
    c[3] = __builtin_bit_cast(float, u23 & 0xffff0000u);
    return c;
}

// ---------------------------------------------------------------------------
// Kernel 1: xg = (x @ W_ihx^T + b_ih + b_hh + [t>0] zbias) * gate_scale, bf16,
// fragment order. (unchanged, passing since round 5)
// ---------------------------------------------------------------------------
__global__ __launch_bounds__(512, 2) void xg_prep(
    const float* __restrict__ x,
    const float* __restrict__ W_ih,
    const float* __restrict__ b_ih,
    const float* __restrict__ b_hh,
    const float* __restrict__ b_mu,
    uint16_t* __restrict__ xg)
{
    const int blk = blockIdx.x;
    const int t   = blk >> 2, bq = blk & 3;
    const int tid = threadIdx.x;
    const int w = tid >> 6, l = tid & 63, lg = l >> 4, ln = l & 15;
    const int b0 = bq * 64;

    bf16x8 wb[4][4];
    float  bias[4];
    #pragma unroll
    for (int q = 0; q < 4; ++q) {
        const int col = q * 128 + w * 16 + ln;
        float zb = 0.f;
        #pragma unroll
        for (int j = 0; j < 32; ++j) zb += b_mu[j] * W_ih[col * KIN + 128 + j];
        bias[q] = b_ih[col] + b_hh[col] + (t > 0 ? zb : 0.f);
        #pragma unroll
        for (int ks = 0; ks < 4; ++ks) {
            bf16x8 v;
            #pragma unroll
            for (int e = 0; e < 8; ++e)
                v[e] = (short)f2bf(W_ih[col * KIN + ks * 32 + lg * 8 + e]);
            wb[ks][q] = v;
        }
    }

    f32x4 acc[4][4];
    const f32x4 vz = {0.f, 0.f, 0.f, 0.f};
    #pragma unroll
    for (int rt = 0; rt < 4; ++rt)
        #pragma unroll
        for (int q = 0; q < 4; ++q) acc[rt][q] = vz;

    #pragma unroll
    for (int ks = 0; ks < 4; ++ks) {
        bf16x8 a[4];
        #pragma unroll
        for (int rt = 0; rt < 4; ++rt) {
            const int brow = b0 + rt * 16 + ln;
            const float* src = x + ((size_t)brow * T_STEPS + t) * OBSD + ks * 32 + lg * 8;
            bf16x8 v;
            #pragma unroll
            for (int e = 0; e < 8; ++e) v[e] = (short)f2bf(src[e]);
            a[rt] = v;
        }
        #pragma unroll
        for (int rt = 0; rt < 4; ++rt)
            #pragma unroll
            for (int q = 0; q < 4; ++q)
                acc[rt][q] = __builtin_amdgcn_mfma_f32_16x16x32_bf16(
                    a[rt], wb[ks][q], acc[rt][q], 0, 0, 0);
    }

    const float gsc[4] = {L2E, L2E, L2E2, L2E};
    uint4* dst = (uint4*)xg + ((size_t)blk * 512 + tid) * 8;
    #pragma unroll
    for (int rt = 0; rt < 4; ++rt) {
        float v0[4], v1[4], v2[4], v3[4];
        #pragma unroll
        for (int e = 0; e < 4; ++e) {
            v0[e] = (acc[rt][0][e] + bias[0]) * gsc[0];
            v1[e] = (acc[rt][1][e] + bias[1]) * gsc[1];
            v2[e] = (acc[rt][2][e] + bias[2]) * gsc[2];
            v3[e] = (acc[rt][3][e] + bias[3]) * gsc[3];
        }
        uint4 o0, o1;
        o0.x = pack2(v0[0], v0[1]); o0.y = pack2(v0[2], v0[3]);
        o0.z = pack2(v1[0], v1[1]); o0.w = pack2(v1[2], v1[3]);
        o1.x = pack2(v2[0], v2[1]); o1.y = pack2(v2[2], v2[3]);
        o1.z = pack2(v3[0], v3[1]); o1.w = pack2(v3[2], v3[3]);
        dst[2 * rt]     = o0;
        dst[2 * rt + 1] = o1;
    }
}

// ---------------------------------------------------------------------------
// Kernel 2: Wr = (W_hh + W_ihz @ W_mu) * gate_scale -> GLOBAL fragment array.
// One 512-thread block; frag (ks*4+q) holds 512 lanes x 16 B.
// ---------------------------------------------------------------------------
__global__ __launch_bounds__(512) void wr_prep(
    const float* __restrict__ W_ih,
    const float* __restrict__ W_hh,
    const float* __restrict__ W_mu,
    uint16_t* __restrict__ wrg)
{
    __shared__ float wmu_s[4096];
    const int tid = threadIdx.x;
    const int w = tid >> 6, l = tid & 63, lg = l >> 4, ln = l & 15;
    for (int i = tid; i < 4096; i += 512) wmu_s[i] = W_mu[i];
    __syncthreads();

    #pragma unroll
    for (int q = 0; q < 4; ++q) {
        const float gs = (q == 2) ? L2E2 : L2E;
        const int col = q * 128 + w * 16 + ln;
        float wzf[32];
        #pragma unroll
        for (int j4 = 0; j4 < 8; ++j4)
            *(float4*)&wzf[j4 * 4] = *(const float4*)&W_ih[col * KIN + 128 + j4 * 4];
        #pragma unroll
        for (int ks = 0; ks < 4; ++ks) {
            float base[8];
            *(float4*)&base[0] = *(const float4*)&W_hh[col * HID + ks * 32 + lg * 8];
            *(float4*)&base[4] = *(const float4*)&W_hh[col * HID + ks * 32 + lg * 8 + 4];
            bf16x8 v;
            #pragma unroll
            for (int e = 0; e < 8; ++e) {
                float s = base[e];
                #pragma unroll
                for (int j = 0; j < 32; ++j)
                    s += wzf[j] * wmu_s[j * HID + ks * 32 + lg * 8 + e];
                v[e] = (short)f2bf(s * gs);
            }
            *(bf16x8*)(wrg + (ks * 4 + q) * 4096 + (w * 64 + l) * 8) = v;
        }
    }
}

// ---------------------------------------------------------------------------
// Kernel 3: recurrence, 400 blocks x 512 thr (32 rows each, 2 blocks/CU) +
// lp/ent tail blocks 400..424. Wr streamed from global (L1/L2-resident).
// h+eps double-buffered -> ONE lgkm-only barrier/step. xg enters as MFMA C.
// ---------------------------------------------------------------------------
__global__ __launch_bounds__(512, 4) void lstm_main(
    const float* __restrict__ eps,
    const float* __restrict__ W_ih,
    const float* __restrict__ W_mu,
    const float* __restrict__ b_mu,
    const float* __restrict__ cov,
    const uint16_t* __restrict__ xg,
    const uint16_t* __restrict__ wrg,
    float* __restrict__ out)
{
    __shared__ __align__(16) char smem[LDS_SZ];
    const int tid = threadIdx.x;

    // ---- lp/ent tail: one row per thread, t-loop ----
    if (blockIdx.x >= 400) {
        const int row = (blockIdx.x - 400) * 512 + tid;
        if (row < BS_TOT) {
            float logdet = 0.f;
            for (int i = 0; i < LATD; ++i) logdet += logf(cov[i]);
            const float lconst = 32.f * LOG2PI + logdet;
            const float ec = 0.5f * 32.f * (1.f + LOG2PI) + 0.5f * logdet;
            const float* ep0 = eps + (size_t)row * LATD;
            float* lpw = out + OUT_LP_OFF  + (size_t)row * 200;
            float* enw = out + OUT_ENT_OFF + (size_t)row * 200;
            for (int t = 0; t < T_STEPS; ++t) {
                const float* ep = ep0 + (size_t)t * BS_TOT * LATD;
                float ps = 0.f;
                #pragma unroll
                for (int k = 0; k < 8; ++k) {
                    const float4 a = *(const float4*)(ep + k * 4);
                    ps += a.x * a.x + a.y * a.y + a.z * a.z + a.w * a.w;
                }
                lpw[t] = -0.5f * (ps + lconst);
                enw[t] = ec;
            }
        }
        return;
    }

    const int w = tid >> 6, l = tid & 63, lg = l >> 4, ln = l & 15;
    const int wp = w;                       // 8 waves = 8 col-groups

    // bijective XCD swizzle over 400 blocks (400 % 8 == 0)
    const int wk = (blockIdx.x & 7) * 50 + (blockIdx.x >> 3);
    const int bq = (wk >> 1) & 3;           // 64-row xg slice
    const int hh = wk & 1;                  // which half of the slice
    const int bs0 = wk * 32;

    // stage W_mu f32 into the H region (16 KB, exactly the dbuf space)
    {
        float* ws = (float*)(smem + H_OFF);
        for (int i = tid; i < 4096; i += 512) ws[i] = W_mu[i];
    }
    __syncthreads();
    const float* wmu_s = (const float*)(smem + H_OFF);

    // WMU bf16 (swizzled) for the mean MFMA B-operand
    for (int i = tid; i < 2048; i += 512) {
        const int col = i >> 6, k2 = (i & 63) * 2;
        const u32 p = pack2(wmu_s[col * HID + k2], wmu_s[col * HID + k2 + 1]);
        *(u32*)(smem + WMU_OFF + (((col << 8) + (k2 << 1)) ^ ((col & 7) << 4))) = p;
    }

    // weg = std * W_ihz * gate_scale (B-frags, K=32), registers
    bf16x8 weg[4];
    {
        float stds[8];
        #pragma unroll
        for (int e = 0; e < 8; ++e) stds[e] = sqrtf(cov[lg * 8 + e]);
        const float gsc[4] = {L2E, L2E, L2E2, L2E};
        #pragma unroll
        for (int q = 0; q < 4; ++q) {
            const int col = q * 128 + wp * 16 + ln;
            bf16x8 v;
            #pragma unroll
            for (int e = 0; e < 8; ++e)
                v[e] = (short)f2bf(W_ih[col * KIN + 128 + lg * 8 + e] * stds[e] * gsc[q]);
            weg[q] = v;
        }
    }

    // mean tiles: waves 0..3 own (rtm, ctm)
    const int rtm = (w >> 1) & 1, ctm = w & 1;
    const int zcol = ctm * 16 + ln;
    const float stdv = sqrtf(cov[zcol]);
    const float bmu  = b_mu[zcol];

    __syncthreads();   // WMU written; wmu_s reads done

    // zero h buf0 + E buf0
    for (int i = tid; i < 2048; i += 512) ((u32*)(smem + H_OFF))[i] = 0;
    for (int i = tid; i < 512;  i += 512) ((u32*)(smem + E_OFF))[i] = 0;

    const f32x4 vz4 = {0.f, 0.f, 0.f, 0.f};
    f32x4 cst[2] = {vz4, vz4};

    const int erow = tid >> 4, ecol = (tid & 15) * 2;   // eps map (32 rows)
    const int ewr = ((erow >> 4) * 64 + (ecol >> 3) * 16 + (erow & 15)) * 16 + (ecol & 7) * 2;
    const uint4* wrp = (const uint4*)wrg;               // frag*512 + wp*64 + l

    __syncthreads();   // zeros visible

    for (int t = 0; t < T_STEPS; ++t) {
        const int pb = t & 1;
        const char* Hp = smem + H_OFF + pb * 8192;
        char*       Hn = smem + H_OFF + (pb ^ 1) * 8192;
        const char* Ep = smem + E_OFF + pb * 2048;
        char*       En = smem + E_OFF + (pb ^ 1) * 2048;

        // ---- issue global loads: xg (C-operands), eps, Wr ks0 ----
        uint4 xv[4];
        const uint4* xp = (const uint4*)xg
            + ((size_t)(t * 4 + bq) * 512 + wp * 64 + l) * 8 + hh * 4;
        #pragma unroll
        for (int i = 0; i < 4; ++i) xv[i] = xp[i];
        const float2 fe = *(const float2*)(eps + ((size_t)t * BS_TOT + bs0 + erow) * LATD + ecol);
        uint4 bw[4], nx[4];
        #pragma unroll
        for (int q = 0; q < 4; ++q) bw[q] = wrp[q * 512 + wp * 64 + l];

        // ---- eg: eps_{t-1} @ weg^T with C = xg ----
        const bf16x8 aE0 = *(const bf16x8*)(Ep + l * 16);
        const bf16x8 aE1 = *(const bf16x8*)(Ep + 1024 + l * 16);
        f32x4 acc[2][4];
        acc[0][0] = __builtin_amdgcn_mfma_f32_16x16x32_bf16(aE0, weg[0], cfrag(xv[0].x, xv[0].y), 0, 0, 0);
        acc[0][1] = __builtin_amdgcn_mfma_f32_16x16x32_bf16(aE0, weg[1], cfrag(xv[0].z, xv[0].w), 0, 0, 0);
        acc[0][2] = __builtin_amdgcn_mfma_f32_16x16x32_bf16(aE0, weg[2], cfrag(xv[1].x, xv[1].y), 0, 0, 0);
        acc[0][3] = __builtin_amdgcn_mfma_f32_16x16x32_bf16(aE0, weg[3], cfrag(xv[1].z, xv[1].w), 0, 0, 0);
        acc[1][0] = __builtin_amdgcn_mfma_f32_16x16x32_bf16(aE1, weg[0], cfrag(xv[2].x, xv[2].y), 0, 0, 0);
        acc[1][1] = __builtin_amdgcn_mfma_f32_16x16x32_bf16(aE1, weg[1], cfrag(xv[2].z, xv[2].w), 0, 0, 0);
        acc[1][2] = __builtin_amdgcn_mfma_f32_16x16x32_bf16(aE1, weg[2], cfrag(xv[3].x, xv[3].y), 0, 0, 0);
        acc[1][3] = __builtin_amdgcn_mfma_f32_16x16x32_bf16(aE1, weg[3], cfrag(xv[3].z, xv[3].w), 0, 0, 0);

        // ---- gates: h_{t-1} @ Wr^T, Wr streamed from L1/L2, depth-1 ----
        #pragma unroll
        for (int ks = 0; ks < 4; ++ks) {
            if (ks < 3) {
                #pragma unroll
                for (int q = 0; q < 4; ++q)
                    nx[q] = wrp[((ks + 1) * 4 + q) * 512 + wp * 64 + l];
            }
            bf16x8 a[2];
            #pragma unroll
            for (int rt = 0; rt < 2; ++rt)
                a[rt] = *(const bf16x8*)(Hp + hswz(rt * 16 + ln, ks * 32 + lg * 8));
            #pragma unroll
            for (int rt = 0; rt < 2; ++rt)
                #pragma unroll
                for (int q = 0; q < 4; ++q)
                    acc[rt][q] = __builtin_amdgcn_mfma_f32_16x16x32_bf16(
                        a[rt], __builtin_bit_cast(bf16x8, bw[q]), acc[rt][q], 0, 0, 0);
            #pragma unroll
            for (int q = 0; q < 4; ++q) bw[q] = nx[q];
        }

        // ---- mean/z for t-1 (waves 0..3) ----
        if (w < 4 && t > 0) {
            f32x4 macc = vz4;
            #pragma unroll
            for (int ks = 0; ks < 4; ++ks) {
                const bf16x8 am = *(const bf16x8*)(Hp + hswz(rtm * 16 + ln, ks * 32 + lg * 8));
                const bf16x8 bm = *(const bf16x8*)(smem + WMU_OFF + hswz(zcol, ks * 32 + lg * 8));
                macc = __builtin_amdgcn_mfma_f32_16x16x32_bf16(am, bm, macc, 0, 0, 0);
            }
            #pragma unroll
            for (int e = 0; e < 4; ++e) {
                const float evv = __builtin_bit_cast(float,
                    (u32)(*(const uint16_t*)(Ep + ((rtm * 64 + (zcol >> 3) * 16 + (lg * 4 + e)) << 4)
                                             + (zcol & 7) * 2)) << 16);
                out[(size_t)(bs0 + rtm * 16 + lg * 4 + e) * 6400 + (t - 1) * 32 + zcol] =
                    macc[e] + bmu + evv * stdv;
            }
        }

        // ---- LSTM elementwise -> h into Hn ----
        #pragma unroll
        for (int rt = 0; rt < 2; ++rt) {
            float hv[4];
            #pragma unroll
            for (int e = 0; e < 4; ++e) {
                const float c = sig2(acc[rt][1][e]) * cst[rt][e]
                              + sig2(acc[rt][0][e]) * tanh2(acc[rt][2][e]);
                cst[rt][e] = c;
                hv[e] = sig2(acc[rt][3][e]) * tanh2(c * L2E2);
            }
            const u32 p01 = cvt_pk_bf16(hv[0], hv[1]);
            const u32 p23 = cvt_pk_bf16(hv[2], hv[3]);
            const int r0 = rt * 16 + lg * 4;
            const int hc = wp * 16 + ln;
            *(uint16_t*)(Hn + hswz(r0,     hc)) = (uint16_t)p01;
            *(uint16_t*)(Hn + hswz(r0 + 1, hc)) = (uint16_t)(p01 >> 16);
            *(uint16_t*)(Hn + hswz(r0 + 2, hc)) = (uint16_t)p23;
            *(uint16_t*)(Hn + hswz(r0 + 3, hc)) = (uint16_t)(p23 >> 16);
        }

        // ---- eps_t -> En (bf16 A-frag order) ----
        *(u32*)(En + ewr) = cvt_pk_bf16(fe.x, fe.y);

        BAR();   // single barrier: Hn/En visible; globals stay in flight
    }

    // epilogue: z for t = 199 (h_199/eps_199 in buf0)
    if (w < 4) {
        const char* Hp = smem + H_OFF;
        const char* Ep = smem + E_OFF;
        f32x4 macc = vz4;
        #pragma unroll
        for (int ks = 0; ks < 4; ++ks) {
            const bf16x8 am = *(const bf16x8*)(Hp + hswz(rtm * 16 + ln, ks * 32 + lg * 8));
            const bf16x8 bm = *(const bf16x8*)(smem + WMU_OFF + hswz(zcol, ks * 32 + lg * 8));
            macc = __builtin_amdgcn_mfma_f32_16x16x32_bf16(am, bm, macc, 0, 0, 0);
        }
        #pragma unroll
        for (int e = 0; e < 4; ++e) {
            const float evv = __builtin_bit_cast(float,
                (u32)(*(const uint16_t*)(Ep + ((rtm * 64 + (zcol >> 3) * 16 + (lg * 4 + e)) << 4)
                                         + (zcol & 7) * 2)) << 16);
            out[(size_t)(bs0 + rtm * 16 + lg * 4 + e) * 6400 + 199 * 32 + zcol] =
                macc[e] + bmu + evv * stdv;
        }
    }
}

extern "C" void kernel_launch(void* const* d_in, const int* in_sizes, int n_in,
                              void* d_out, int out_size, void* d_ws, size_t ws_size,
                              hipStream_t stream) {
    const float* x    = (const float*)d_in[0];
    const float* eps  = (const float*)d_in[1];
    const float* W_ih = (const float*)d_in[2];
    const float* W_hh = (const float*)d_in[3];
    const float* b_ih = (const float*)d_in[4];
    const float* b_hh = (const float*)d_in[5];
    const float* W_mu = (const float*)d_in[6];
    const float* b_mu = (const float*)d_in[7];
    const float* cov  = (const float*)d_in[8];
    float* out = (float*)d_out;
    uint16_t* xg  = (uint16_t*)d_ws;                          // 52,428,800 B
    uint16_t* wrg = (uint16_t*)((char*)d_ws + WS_XG_BYTES);   // +131,072 B

    hipLaunchKernelGGL(xg_prep, dim3(800), dim3(512), 0, stream, x, W_ih, b_ih, b_hh, b_mu, xg);
    hipLaunchKernelGGL(wr_prep, dim3(1), dim3(512), 0, stream, W_ih, W_hh, W_mu, wrg);
    hipLaunchKernelGGL(lstm_main, dim3(425), dim3(512), 0, stream,
                       eps, W_ih, W_mu, b_mu, cov, xg, wrg, out);
}